// Round 2
// baseline (318.654 us; speedup 1.0000x reference)
//
#include <hip/hip_runtime.h>

typedef __bf16 bf16;
typedef __bf16 bf16x8 __attribute__((ext_vector_type(8)));
typedef float f32x4 __attribute__((ext_vector_type(4)));

// Problem constants: B_Nq = B_Ns = 16, C = 512, H = W = 32, P = 1024, TAU = 0.5
// TAU*C = 256.  All I/O fp32; internal GEMMs in bf16 MFMA (fp32 accumulate).

__device__ inline float wave_reduce_sum(float v) {
#pragma unroll
    for (int m = 32; m >= 1; m >>= 1) v += __shfl_xor(v, m, 64);
    return v;
}
__device__ inline float wave_reduce_max(float v) {
#pragma unroll
    for (int m = 32; m >= 1; m >>= 1) v = fmaxf(v, __shfl_xor(v, m, 64));
    return v;
}

// K0: convert f_q fp32 -> bf16 (GEMM1 A operand)
__global__ void k_cvt_fq(const float* __restrict__ fq, bf16* __restrict__ fq16) {
    int idx = blockIdx.x * 256 + threadIdx.x;
    fq16[idx] = (bf16)fq[idx];
}

// K1: fs_mean[c,p] = mean_b f_s[b,c,p]; write fp32 + bf16 copies.
__global__ void k_fsmean(const float* __restrict__ fs, float* __restrict__ fsm32,
                         bf16* __restrict__ fsm16) {
    int idx = blockIdx.x * 256 + threadIdx.x;  // 0..524287  (c*1024+p)
    float s = 0.f;
#pragma unroll
    for (int b = 0; b < 16; ++b) s += fs[(size_t)b * 524288 + idx];
    s *= (1.f / 16.f);
    fsm32[idx] = s;
    fsm16[idx] = (bf16)s;
}

// K2: transpose fs_mean bf16 [512,1024] -> [1024,512]
__global__ void k_transpose(const bf16* __restrict__ src, bf16* __restrict__ dst) {
    __shared__ bf16 tile[32][33];
    int p0 = blockIdx.x * 32, c0 = blockIdx.y * 32;
    int tx = threadIdx.x, ty = threadIdx.y;  // 32 x 8
#pragma unroll
    for (int i = 0; i < 4; ++i)
        tile[ty + 8 * i][tx] = src[(size_t)(c0 + ty + 8 * i) * 1024 + p0 + tx];
    __syncthreads();
#pragma unroll
    for (int i = 0; i < 4; ++i)
        dst[(size_t)(p0 + ty + 8 * i) * 512 + c0 + tx] = tile[tx][ty + 8 * i];
}

// K2b: u[c] = w_sca_q[c]*w_sca_k[c]*rowmean(fs_mean[c,:]) / (TAU*C)
__global__ void k_u(const float* __restrict__ fsm32, const float* __restrict__ wsq,
                    const float* __restrict__ wsk, float* __restrict__ u) {
    int c = blockIdx.x;
    int t = threadIdx.x;
    float s = 0.f;
#pragma unroll
    for (int j = 0; j < 4; ++j) s += fsm32[(size_t)c * 1024 + t + 256 * j];
    s = wave_reduce_sum(s);
    __shared__ float red[4];
    int w = t >> 6, lane = t & 63;
    if (lane == 0) red[w] = s;
    __syncthreads();
    if (t == 0) {
        float rm = (red[0] + red[1] + red[2] + red[3]) * (1.f / 1024.f);
        u[c] = wsq[c] * wsk[c] * rm * (1.f / 256.f);
    }
}

// K3: G[b,c,d] = sum_p f_q[b,c,p] * fs_mean[d,p]   (NT MFMA GEMM, K=1024)
// block = 256 (4 waves), tile 64(c) x 64(d); wave w owns c rows [16w,16w+16)
__global__ void k_gemm1(const bf16* __restrict__ fq16, const bf16* __restrict__ fsm16,
                        float* __restrict__ G) {
    int dt = blockIdx.x, ct = blockIdx.y, b = blockIdx.z;
    int w = threadIdx.x >> 6, lane = threadIdx.x & 63;
    int quad = lane >> 4, r15 = lane & 15;
    const bf16* arow = fq16 + ((size_t)(b * 512 + ct * 64 + w * 16 + r15)) * 1024 + quad * 8;
    const bf16* brow = fsm16 + ((size_t)(dt * 64 + r15)) * 1024 + quad * 8;
    f32x4 acc[4] = {};
    for (int k = 0; k < 1024; k += 32) {
        bf16x8 a = *(const bf16x8*)(arow + k);
#pragma unroll
        for (int f = 0; f < 4; ++f) {
            bf16x8 bb = *(const bf16x8*)(brow + (size_t)f * 16 * 1024 + k);
            acc[f] = __builtin_amdgcn_mfma_f32_16x16x32_bf16(a, bb, acc[f], 0, 0, 0);
        }
    }
    // D layout: row=(lane>>4)*4+i, col=lane&15
    float* gout = G + ((size_t)(b * 512 + ct * 64 + w * 16 + quad * 4)) * 512 + dt * 64 + r15;
#pragma unroll
    for (int f = 0; f < 4; ++f)
#pragma unroll
        for (int i = 0; i < 4; ++i) gout[i * 512 + f * 16] = acc[f][i];
}

// K4: per-row softmax over d of S[b,c,d]=G*wq[c]*wk[d]/P, then fold wv[d] -> Acw bf16
__global__ void k_softmax_ac(const float* __restrict__ G, const float* __restrict__ wq,
                             const float* __restrict__ wk, const float* __restrict__ wv,
                             bf16* __restrict__ Acw) {
    int row = blockIdx.x * 4 + (threadIdx.x >> 6);  // b*512 + c
    int lane = threadIdx.x & 63;
    int c = row & 511;
    const float* g = G + (size_t)row * 512;
    float sc = wq[c] * (1.f / 1024.f);
    float v[8];
    float mx = -3.4e38f;
#pragma unroll
    for (int j = 0; j < 8; ++j) {
        int d = lane + 64 * j;
        v[j] = g[d] * sc * wk[d];
        mx = fmaxf(mx, v[j]);
    }
    mx = wave_reduce_max(mx);
    float sum = 0.f;
#pragma unroll
    for (int j = 0; j < 8; ++j) {
        v[j] = __expf(v[j] - mx);
        sum += v[j];
    }
    sum = wave_reduce_sum(sum);
    float inv = 1.f / sum;
    bf16* o = Acw + (size_t)row * 512;
#pragma unroll
    for (int j = 0; j < 8; ++j) {
        int d = lane + 64 * j;
        o[d] = (bf16)(v[j] * inv * wv[d]);
    }
}

// K5: f_cca[b,c,p] = sum_d Acw[b,c,d]*fs_meanT[p,d]  (NT MFMA GEMM, K=512)
// fused epilogue: out = f_q + lam*f_cca (fp32); also store fp32 f_cca
__global__ void k_gemm2(const bf16* __restrict__ Acw, const bf16* __restrict__ fsmT,
                        const float* __restrict__ fq, const float* __restrict__ lamp,
                        float* __restrict__ fcca, float* __restrict__ out) {
    int pt = blockIdx.x, ct = blockIdx.y, b = blockIdx.z;
    int w = threadIdx.x >> 6, lane = threadIdx.x & 63;
    int quad = lane >> 4, r15 = lane & 15;
    const bf16* arow = Acw + ((size_t)(b * 512 + ct * 64 + w * 16 + r15)) * 512 + quad * 8;
    const bf16* brow = fsmT + ((size_t)(pt * 64 + r15)) * 512 + quad * 8;
    f32x4 acc[4] = {};
    for (int k = 0; k < 512; k += 32) {
        bf16x8 a = *(const bf16x8*)(arow + k);
#pragma unroll
        for (int f = 0; f < 4; ++f) {
            bf16x8 bb = *(const bf16x8*)(brow + (size_t)f * 16 * 512 + k);
            acc[f] = __builtin_amdgcn_mfma_f32_16x16x32_bf16(a, bb, acc[f], 0, 0, 0);
        }
    }
    float lam = lamp[0];
    int c0 = ct * 64 + w * 16 + quad * 4;
    int p0 = pt * 64 + r15;
#pragma unroll
    for (int f = 0; f < 4; ++f)
#pragma unroll
        for (int i = 0; i < 4; ++i) {
            size_t idx = ((size_t)(b * 512 + c0 + i)) * 1024 + p0 + f * 16;
            float val = acc[f][i];
            fcca[idx] = val;
            out[idx] = fq[idx] + lam * val;
        }
}

// K6: r[b,c] = mean_p f_cca[b,c,p]
__global__ void k_rmean(const float* __restrict__ fcca, float* __restrict__ r) {
    int row = blockIdx.x * 4 + (threadIdx.x >> 6);  // b*512+c
    int lane = threadIdx.x & 63;
    const float* src = fcca + (size_t)row * 1024;
    float s = 0.f;
#pragma unroll
    for (int j = 0; j < 16; ++j) s += src[lane + 64 * j];
    s = wave_reduce_sum(s);
    if (lane == 0) r[row] = s * (1.f / 1024.f);
}

// K7: alpha_logits[b,p] += sum_{c chunk} f_cca[b,c,p]*u[c]
__global__ void k_alpha_partial(const float* __restrict__ fcca, const float* __restrict__ u,
                                float* __restrict__ alog) {
    int b = blockIdx.z;
    int c0 = blockIdx.y * 64;
    int p = blockIdx.x * 256 + threadIdx.x;
    const float* base = fcca + ((size_t)(b * 512 + c0)) * 1024 + p;
    float s = 0.f;
#pragma unroll 8
    for (int cc = 0; cc < 64; ++cc) s += base[(size_t)cc * 1024] * u[c0 + cc];
    atomicAdd(&alog[b * 1024 + p], s);
}

// K8: beta_logits[b,q] += sum_{c chunk} r[b,c]*wsq[c]*wsk[c]/(TAU*C) * fs_mean[c,q]
__global__ void k_beta_partial(const float* __restrict__ fsm32, const float* __restrict__ r,
                               const float* __restrict__ wsq, const float* __restrict__ wsk,
                               float* __restrict__ blog) {
    int b = blockIdx.z;
    int c0 = blockIdx.y * 64;
    int q = blockIdx.x * 256 + threadIdx.x;
    float s = 0.f;
#pragma unroll 8
    for (int cc = 0; cc < 64; ++cc) {
        int c = c0 + cc;
        float coef = r[b * 512 + c] * wsq[c] * wsk[c] * (1.f / 256.f);
        s += coef * fsm32[(size_t)c * 1024 + q];
    }
    atomicAdd(&blog[b * 1024 + q], s);
}

// K9: block z<16: alpha row softmax -> out; z>=16: beta row softmax -> fp32 ws
__global__ void k_softmax_rows(const float* __restrict__ alog, const float* __restrict__ blog,
                               float* __restrict__ alpha_out, float* __restrict__ beta) {
    int z = blockIdx.x;
    int t = threadIdx.x;
    int w = t >> 6, lane = t & 63;
    const float* src = (z < 16) ? (alog + (size_t)z * 1024) : (blog + (size_t)(z - 16) * 1024);
    float v[4];
    float mx = -3.4e38f;
#pragma unroll
    for (int j = 0; j < 4; ++j) {
        v[j] = src[t + 256 * j];
        mx = fmaxf(mx, v[j]);
    }
    __shared__ float red[4];
    float wm = wave_reduce_max(mx);
    if (lane == 0) red[w] = wm;
    __syncthreads();
    mx = fmaxf(fmaxf(red[0], red[1]), fmaxf(red[2], red[3]));
    float s = 0.f;
#pragma unroll
    for (int j = 0; j < 4; ++j) {
        v[j] = __expf(v[j] - mx);
        s += v[j];
    }
    __syncthreads();
    float ws_ = wave_reduce_sum(s);
    if (lane == 0) red[w] = ws_;
    __syncthreads();
    s = red[0] + red[1] + red[2] + red[3];
    float inv = 1.f / s;
    if (z < 16) {
#pragma unroll
        for (int j = 0; j < 4; ++j) alpha_out[(size_t)z * 1024 + t + 256 * j] = v[j] * inv;
    } else {
#pragma unroll
        for (int j = 0; j < 4; ++j) beta[(size_t)(z - 16) * 1024 + t + 256 * j] = v[j] * inv;
    }
}

// K10: beta_mean[q] = mean_b beta[b,q]; broadcast to 16 rows of output
__global__ void k_betamean(const float* __restrict__ beta, float* __restrict__ out) {
    int q = blockIdx.x * 256 + threadIdx.x;  // 0..1023
    float s = 0.f;
#pragma unroll
    for (int b = 0; b < 16; ++b) s += beta[b * 1024 + q];
    float val = s * (1.f / 16.f);
#pragma unroll
    for (int si = 0; si < 16; ++si) out[(size_t)si * 1024 + q] = val;
}

extern "C" void kernel_launch(void* const* d_in, const int* in_sizes, int n_in,
                              void* d_out, int out_size, void* d_ws, size_t ws_size,
                              hipStream_t stream) {
    const float* f_q = (const float*)d_in[0];
    const float* f_s = (const float*)d_in[1];
    const float* w_cca_q = (const float*)d_in[2];
    const float* w_cca_k = (const float*)d_in[3];
    const float* w_cca_v = (const float*)d_in[4];
    const float* w_sca_q = (const float*)d_in[5];
    const float* w_sca_k = (const float*)d_in[6];
    const float* lamp = (const float*)d_in[7];

    char* ws = (char*)d_ws;
    float* fsm32 = (float*)(ws + 0);                 //  2 MB  [512,1024] fp32
    bf16* fsm16 = (bf16*)(ws + 2097152);             //  1 MB  [512,1024] bf16
    bf16* fsmT = (bf16*)(ws + 3145728);              //  1 MB  [1024,512] bf16
    float* G = (float*)(ws + 4194304);               // 16 MB  [16,512,512] fp32
    bf16* Acw = (bf16*)(ws + 20971520);              //  8 MB  [16,512,512] bf16
    float* fcca = (float*)(ws + 29360128);           // 33.5MB [16,512,1024] fp32
    bf16* fq16 = (bf16*)(ws + 62914560);             // 16.8MB [16,512,1024] bf16
    float* u = (float*)(ws + 79691776);              //  2 KB  [512]
    float* r = (float*)(ws + 79693824);              // 32 KB  [16,512]
    float* alog = (float*)(ws + 79726592);           // 64 KB  [16,1024]
    float* blog = (float*)(ws + 79792128);           // 64 KB  [16,1024]
    float* beta = (float*)(ws + 79857664);           // 64 KB  [16,1024]

    float* out_fq = (float*)d_out;                   // [16,512,1024]
    float* out_alpha = out_fq + 8388608;             // [16,1024]
    float* out_bmean = out_fq + 8404992;             // [16,1024]

    // zero the atomic accumulators (alog+blog contiguous)
    hipMemsetAsync(ws + 79726592, 0, 131072, stream);

    k_cvt_fq<<<32768, 256, 0, stream>>>(f_q, fq16);
    k_fsmean<<<2048, 256, 0, stream>>>(f_s, fsm32, fsm16);
    k_transpose<<<dim3(32, 16), dim3(32, 8), 0, stream>>>(fsm16, fsmT);
    k_u<<<512, 256, 0, stream>>>(fsm32, w_sca_q, w_sca_k, u);
    k_gemm1<<<dim3(8, 8, 16), 256, 0, stream>>>(fq16, fsm16, G);
    k_softmax_ac<<<2048, 256, 0, stream>>>(G, w_cca_q, w_cca_k, w_cca_v, Acw);
    k_gemm2<<<dim3(16, 8, 16), 256, 0, stream>>>(Acw, fsmT, f_q, lamp, fcca, out_fq);
    k_rmean<<<2048, 256, 0, stream>>>(fcca, r);
    k_alpha_partial<<<dim3(4, 8, 16), 256, 0, stream>>>(fcca, u, alog);
    k_beta_partial<<<dim3(4, 8, 16), 256, 0, stream>>>(fsm32, r, w_sca_q, w_sca_k, blog);
    k_softmax_rows<<<32, 256, 0, stream>>>(alog, blog, out_alpha, beta);
    k_betamean<<<4, 256, 0, stream>>>(beta, out_bmean);
}

// Round 3
// 232.014 us; speedup vs baseline: 1.3734x; 1.3734x over previous
//
#include <hip/hip_runtime.h>

typedef __bf16 bf16;
typedef __bf16 bf16x8 __attribute__((ext_vector_type(8)));
typedef float f32x4 __attribute__((ext_vector_type(4)));

// B_Nq = B_Ns = 16, C = 512, P = 1024, TAU*C = 256. I/O fp32; GEMMs bf16 MFMA.

#define GLL16(g, l)                                                             \
    __builtin_amdgcn_global_load_lds((const __attribute__((address_space(1))) void*)(g), \
                                     (__attribute__((address_space(3))) void*)(l), 16, 0, 0)

__device__ inline float wave_reduce_sum(float v) {
#pragma unroll
    for (int m = 32; m >= 1; m >>= 1) v += __shfl_xor(v, m, 64);
    return v;
}
__device__ inline float wave_reduce_max(float v) {
#pragma unroll
    for (int m = 32; m >= 1; m >>= 1) v = fmaxf(v, __shfl_xor(v, m, 64));
    return v;
}

// K0: f_q fp32 -> bf16
__global__ void k_cvt_fq(const float* __restrict__ fq, bf16* __restrict__ fq16) {
    int idx = blockIdx.x * 256 + threadIdx.x;
    fq16[idx] = (bf16)fq[idx];
}

// K1: fs_mean[c,p] = mean_b f_s[b,c,p]; fp32 + bf16 copies
__global__ void k_fsmean(const float* __restrict__ fs, float* __restrict__ fsm32,
                         bf16* __restrict__ fsm16) {
    int idx = blockIdx.x * 256 + threadIdx.x;
    float s = 0.f;
#pragma unroll
    for (int b = 0; b < 16; ++b) s += fs[(size_t)b * 524288 + idx];
    s *= (1.f / 16.f);
    fsm32[idx] = s;
    fsm16[idx] = (bf16)s;
}

// K2: transpose fs_mean bf16 [512,1024] -> [1024,512]
__global__ void k_transpose(const bf16* __restrict__ src, bf16* __restrict__ dst) {
    __shared__ bf16 tile[32][33];
    int p0 = blockIdx.x * 32, c0 = blockIdx.y * 32;
    int tx = threadIdx.x, ty = threadIdx.y;  // 32 x 8
#pragma unroll
    for (int i = 0; i < 4; ++i)
        tile[ty + 8 * i][tx] = src[(size_t)(c0 + ty + 8 * i) * 1024 + p0 + tx];
    __syncthreads();
#pragma unroll
    for (int i = 0; i < 4; ++i)
        dst[(size_t)(p0 + ty + 8 * i) * 512 + c0 + tx] = tile[tx][ty + 8 * i];
}

// K2b: rm[c] = rowmean(fs_mean[c,:]); u[c] = wsq[c]*wsk[c]*rm[c]/256
__global__ void k_u(const float* __restrict__ fsm32, const float* __restrict__ wsq,
                    const float* __restrict__ wsk, float* __restrict__ u,
                    float* __restrict__ rm) {
    int c = blockIdx.x;
    int t = threadIdx.x;
    float s = 0.f;
#pragma unroll
    for (int j = 0; j < 4; ++j) s += fsm32[(size_t)c * 1024 + t + 256 * j];
    s = wave_reduce_sum(s);
    __shared__ float red[4];
    int w = t >> 6, lane = t & 63;
    if (lane == 0) red[w] = s;
    __syncthreads();
    if (t == 0) {
        float rmv = (red[0] + red[1] + red[2] + red[3]) * (1.f / 1024.f);
        rm[c] = rmv;
        u[c] = wsq[c] * wsk[c] * rmv * (1.f / 256.f);
    }
}

// K3: G[b,c,d] = sum_p fq16[b,c,p]*fsm16[d,p]  — 128x128 LDS-tiled NT GEMM, K=1024
__global__ void k_gemm1(const bf16* __restrict__ A, const bf16* __restrict__ B,
                        float* __restrict__ G) {
    __shared__ alignas(16) bf16 As[128 * 32];
    __shared__ alignas(16) bf16 Bs[128 * 32];
    const int dt = blockIdx.x, ct = blockIdx.y, b = blockIdx.z;
    const int t = threadIdx.x;
    const int wave = t >> 6, lane = t & 63;
    const int wr = wave >> 1, wc = wave & 1;
    const int quad = lane >> 4, r15 = lane & 15;
    const bf16* Abase = A + ((size_t)(b * 512 + ct * 128)) * 1024;
    const bf16* Bbase = B + ((size_t)(dt * 128)) * 1024;
    const int srow = t >> 2, skc = (t & 3) * 8;  // staging row/chunk
    f32x4 acc[4][4] = {};

    for (int k0 = 0; k0 < 1024; k0 += 32) {
        GLL16(Abase + (size_t)srow * 1024 + k0 + skc, As + t * 8);
        GLL16(Abase + (size_t)(srow + 64) * 1024 + k0 + skc, As + (t + 256) * 8);
        GLL16(Bbase + (size_t)srow * 1024 + k0 + skc, Bs + t * 8);
        GLL16(Bbase + (size_t)(srow + 64) * 1024 + k0 + skc, Bs + (t + 256) * 8);
        __syncthreads();
        bf16x8 af[4], bfr[4];
#pragma unroll
        for (int f = 0; f < 4; ++f) {
            af[f] = *(const bf16x8*)(As + (wr * 64 + f * 16 + r15) * 32 + quad * 8);
            bfr[f] = *(const bf16x8*)(Bs + (wc * 64 + f * 16 + r15) * 32 + quad * 8);
        }
#pragma unroll
        for (int i = 0; i < 4; ++i)
#pragma unroll
            for (int j = 0; j < 4; ++j)
                acc[i][j] = __builtin_amdgcn_mfma_f32_16x16x32_bf16(af[i], bfr[j], acc[i][j], 0, 0, 0);
        __syncthreads();
    }
    float* gout = G + ((size_t)(b * 512 + ct * 128 + wr * 64 + quad * 4)) * 512 +
                  dt * 128 + wc * 64 + r15;
#pragma unroll
    for (int i = 0; i < 4; ++i)
#pragma unroll
        for (int ii = 0; ii < 4; ++ii)
#pragma unroll
            for (int j = 0; j < 4; ++j)
                gout[(size_t)(i * 16 + ii) * 512 + j * 16] = acc[i][j][ii];
}

// K4: row softmax of G*wq[c]*wk[d]/P -> Acw (bf16, folds wv); also r[b,c]=sum_d Acw*rm[d]
__global__ void k_softmax_ac(const float* __restrict__ G, const float* __restrict__ wq,
                             const float* __restrict__ wk, const float* __restrict__ wv,
                             const float* __restrict__ rm, bf16* __restrict__ Acw,
                             float* __restrict__ r) {
    int row = blockIdx.x * 4 + (threadIdx.x >> 6);  // b*512 + c
    int lane = threadIdx.x & 63;
    int c = row & 511;
    const float* g = G + (size_t)row * 512;
    float sc = wq[c] * (1.f / 1024.f);
    float v[8];
    float mx = -3.4e38f;
#pragma unroll
    for (int j = 0; j < 8; ++j) {
        int d = lane + 64 * j;
        v[j] = g[d] * sc * wk[d];
        mx = fmaxf(mx, v[j]);
    }
    mx = wave_reduce_max(mx);
    float sum = 0.f;
#pragma unroll
    for (int j = 0; j < 8; ++j) {
        v[j] = __expf(v[j] - mx);
        sum += v[j];
    }
    sum = wave_reduce_sum(sum);
    float inv = 1.f / sum;
    bf16* o = Acw + (size_t)row * 512;
    float rsum = 0.f;
#pragma unroll
    for (int j = 0; j < 8; ++j) {
        int d = lane + 64 * j;
        float aw = v[j] * inv * wv[d];
        o[d] = (bf16)aw;
        rsum += aw * rm[d];
    }
    rsum = wave_reduce_sum(rsum);
    if (lane == 0) r[row] = rsum;
}

// K5: t[b,d] = sum_c u[c]*Acw[b,c,d]
__global__ void k_t(const bf16* __restrict__ Acw, const float* __restrict__ u,
                    float* __restrict__ tb) {
    int b = blockIdx.y, d = blockIdx.x * 256 + threadIdx.x;
    const bf16* base = Acw + (size_t)b * 512 * 512 + d;
    float s = 0.f;
#pragma unroll 8
    for (int c = 0; c < 512; ++c) s += u[c] * (float)base[(size_t)c * 512];
    tb[b * 512 + d] = s;
}

// K6: out[b,c,p] = fq + lam * sum_d Acw[b,c,d]*fsmT[p,d] — 128x128 LDS-tiled, K=512
__global__ void k_gemm2(const bf16* __restrict__ A, const bf16* __restrict__ B,
                        const float* __restrict__ fq, const float* __restrict__ lamp,
                        float* __restrict__ out) {
    __shared__ alignas(16) bf16 As[128 * 32];
    __shared__ alignas(16) bf16 Bs[128 * 32];
    const int pt = blockIdx.x, ct = blockIdx.y, b = blockIdx.z;
    const int t = threadIdx.x;
    const int wave = t >> 6, lane = t & 63;
    const int wr = wave >> 1, wc = wave & 1;
    const int quad = lane >> 4, r15 = lane & 15;
    const bf16* Abase = A + ((size_t)(b * 512 + ct * 128)) * 512;
    const bf16* Bbase = B + ((size_t)(pt * 128)) * 512;
    const int srow = t >> 2, skc = (t & 3) * 8;
    f32x4 acc[4][4] = {};

    for (int k0 = 0; k0 < 512; k0 += 32) {
        GLL16(Abase + (size_t)srow * 512 + k0 + skc, As + t * 8);
        GLL16(Abase + (size_t)(srow + 64) * 512 + k0 + skc, As + (t + 256) * 8);
        GLL16(Bbase + (size_t)srow * 512 + k0 + skc, Bs + t * 8);
        GLL16(Bbase + (size_t)(srow + 64) * 512 + k0 + skc, Bs + (t + 256) * 8);
        __syncthreads();
        bf16x8 af[4], bfr[4];
#pragma unroll
        for (int f = 0; f < 4; ++f) {
            af[f] = *(const bf16x8*)(As + (wr * 64 + f * 16 + r15) * 32 + quad * 8);
            bfr[f] = *(const bf16x8*)(Bs + (wc * 64 + f * 16 + r15) * 32 + quad * 8);
        }
#pragma unroll
        for (int i = 0; i < 4; ++i)
#pragma unroll
            for (int j = 0; j < 4; ++j)
                acc[i][j] = __builtin_amdgcn_mfma_f32_16x16x32_bf16(af[i], bfr[j], acc[i][j], 0, 0, 0);
        __syncthreads();
    }
    float lam = lamp[0];
    size_t obase = ((size_t)(b * 512 + ct * 128 + wr * 64 + quad * 4)) * 1024 +
                   pt * 128 + wc * 64 + r15;
#pragma unroll
    for (int i = 0; i < 4; ++i)
#pragma unroll
        for (int ii = 0; ii < 4; ++ii)
#pragma unroll
            for (int j = 0; j < 4; ++j) {
                size_t idx = obase + (size_t)(i * 16 + ii) * 1024 + j * 16;
                out[idx] = fq[idx] + lam * acc[i][j][ii];
            }
}

// K7: z<16: alog[b,p]=sum_d t[b,d]*fsm[d,p]; z>=16: blog[b,q]=sum_c s[b,c]*fsm[c,q]
__global__ void k_logits(const float* __restrict__ tb, const float* __restrict__ r,
                         const float* __restrict__ wsq, const float* __restrict__ wsk,
                         const float* __restrict__ fsm32, float* __restrict__ alog,
                         float* __restrict__ blog) {
    int z = blockIdx.y, pq = blockIdx.x * 256 + threadIdx.x;
    if (z < 16) {
        const float* tv = tb + z * 512;
        float s = 0.f;
#pragma unroll 8
        for (int d = 0; d < 512; ++d) s += tv[d] * fsm32[(size_t)d * 1024 + pq];
        alog[z * 1024 + pq] = s;
    } else {
        int b = z - 16;
        float s = 0.f;
#pragma unroll 8
        for (int c = 0; c < 512; ++c) {
            float coef = r[b * 512 + c] * wsq[c] * wsk[c] * (1.f / 256.f);
            s += coef * fsm32[(size_t)c * 1024 + pq];
        }
        blog[b * 1024 + pq] = s;
    }
}

// K8: z<16: alpha softmax -> out; z>=16: beta softmax -> ws
__global__ void k_softmax_rows(const float* __restrict__ alog, const float* __restrict__ blog,
                               float* __restrict__ alpha_out, float* __restrict__ beta) {
    int z = blockIdx.x;
    int t = threadIdx.x;
    int w = t >> 6, lane = t & 63;
    const float* src = (z < 16) ? (alog + (size_t)z * 1024) : (blog + (size_t)(z - 16) * 1024);
    float v[4];
    float mx = -3.4e38f;
#pragma unroll
    for (int j = 0; j < 4; ++j) {
        v[j] = src[t + 256 * j];
        mx = fmaxf(mx, v[j]);
    }
    __shared__ float red[4];
    float wm = wave_reduce_max(mx);
    if (lane == 0) red[w] = wm;
    __syncthreads();
    mx = fmaxf(fmaxf(red[0], red[1]), fmaxf(red[2], red[3]));
    float s = 0.f;
#pragma unroll
    for (int j = 0; j < 4; ++j) {
        v[j] = __expf(v[j] - mx);
        s += v[j];
    }
    __syncthreads();
    float ws_ = wave_reduce_sum(s);
    if (lane == 0) red[w] = ws_;
    __syncthreads();
    s = red[0] + red[1] + red[2] + red[3];
    float inv = 1.f / s;
    if (z < 16) {
#pragma unroll
        for (int j = 0; j < 4; ++j) alpha_out[(size_t)z * 1024 + t + 256 * j] = v[j] * inv;
    } else {
#pragma unroll
        for (int j = 0; j < 4; ++j) beta[(size_t)(z - 16) * 1024 + t + 256 * j] = v[j] * inv;
    }
}

// K9: beta_mean broadcast
__global__ void k_betamean(const float* __restrict__ beta, float* __restrict__ out) {
    int q = blockIdx.x * 256 + threadIdx.x;
    float s = 0.f;
#pragma unroll
    for (int b = 0; b < 16; ++b) s += beta[b * 1024 + q];
    float val = s * (1.f / 16.f);
#pragma unroll
    for (int si = 0; si < 16; ++si) out[(size_t)si * 1024 + q] = val;
}

extern "C" void kernel_launch(void* const* d_in, const int* in_sizes, int n_in,
                              void* d_out, int out_size, void* d_ws, size_t ws_size,
                              hipStream_t stream) {
    const float* f_q = (const float*)d_in[0];
    const float* f_s = (const float*)d_in[1];
    const float* w_cca_q = (const float*)d_in[2];
    const float* w_cca_k = (const float*)d_in[3];
    const float* w_cca_v = (const float*)d_in[4];
    const float* w_sca_q = (const float*)d_in[5];
    const float* w_sca_k = (const float*)d_in[6];
    const float* lamp = (const float*)d_in[7];

    char* ws = (char*)d_ws;
    float* fsm32 = (float*)(ws + 0);             //  2 MB   [512,1024]
    bf16* fsm16 = (bf16*)(ws + 2097152);         //  1 MB
    bf16* fsmT = (bf16*)(ws + 3145728);          //  1 MB   [1024,512]
    float* G = (float*)(ws + 4194304);           // 16 MB   [16,512,512]
    bf16* Acw = (bf16*)(ws + 20971520);          //  8 MB   [16,512,512]
    bf16* fq16 = (bf16*)(ws + 29360128);         // 16.8 MB [16,512,1024]
    float* rm = (float*)(ws + 46137344);         //  2 KB
    float* u = (float*)(ws + 46139392);          //  2 KB
    float* r = (float*)(ws + 46141440);          // 32 KB   [16,512]
    float* tb = (float*)(ws + 46174208);         // 32 KB   [16,512]
    float* alog = (float*)(ws + 46206976);       // 64 KB
    float* blog = (float*)(ws + 46272512);       // 64 KB
    float* beta = (float*)(ws + 46338048);       // 64 KB

    float* out_fq = (float*)d_out;
    float* out_alpha = out_fq + 8388608;
    float* out_bmean = out_fq + 8404992;

    k_cvt_fq<<<32768, 256, 0, stream>>>(f_q, fq16);
    k_fsmean<<<2048, 256, 0, stream>>>(f_s, fsm32, fsm16);
    k_transpose<<<dim3(32, 16), dim3(32, 8), 0, stream>>>(fsm16, fsmT);
    k_u<<<512, 256, 0, stream>>>(fsm32, w_sca_q, w_sca_k, u, rm);
    k_gemm1<<<dim3(4, 4, 16), 256, 0, stream>>>(fq16, fsm16, G);
    k_softmax_ac<<<2048, 256, 0, stream>>>(G, w_cca_q, w_cca_k, w_cca_v, rm, Acw, r);
    k_t<<<dim3(2, 16), 256, 0, stream>>>(Acw, u, tb);
    k_gemm2<<<dim3(8, 4, 16), 256, 0, stream>>>(Acw, fsmT, f_q, lamp, out_fq);
    k_logits<<<dim3(4, 32), 256, 0, stream>>>(tb, r, w_sca_q, w_sca_k, fsm32, alog, blog);
    k_softmax_rows<<<32, 256, 0, stream>>>(alog, blog, out_alpha, beta);
    k_betamean<<<4, 256, 0, stream>>>(beta, out_bmean);
}

// Round 4
// 204.641 us; speedup vs baseline: 1.5571x; 1.1338x over previous
//
#include <hip/hip_runtime.h>

typedef __bf16 bf16;
typedef __bf16 bf16x4 __attribute__((ext_vector_type(4)));
typedef __bf16 bf16x8 __attribute__((ext_vector_type(8)));
typedef float f32x4 __attribute__((ext_vector_type(4)));

// B_Nq = B_Ns = 16, C = 512, P = 1024, TAU*C = 256. I/O fp32; GEMMs bf16 MFMA.

#define GLL16(g, l)                                                             \
    __builtin_amdgcn_global_load_lds((const __attribute__((address_space(1))) void*)(g), \
                                     (__attribute__((address_space(3))) void*)(l), 16, 0, 0)

__device__ inline float wave_reduce_sum(float v) {
#pragma unroll
    for (int m = 32; m >= 1; m >>= 1) v += __shfl_xor(v, m, 64);
    return v;
}
__device__ inline float wave_reduce_max(float v) {
#pragma unroll
    for (int m = 32; m >= 1; m >>= 1) v = fmaxf(v, __shfl_xor(v, m, 64));
    return v;
}

// K0: fused prep — fs_mean (fp32+bf16), fs_mean transpose (bf16), f_q cvt to bf16.
// grid (32 p-tiles, 16 c-tiles), block 256.
__global__ void k_prep(const float* __restrict__ fs, const float* __restrict__ fq,
                       float* __restrict__ fsm32, bf16* __restrict__ fsm16,
                       bf16* __restrict__ fsmT, bf16* __restrict__ fq16) {
    __shared__ bf16 tile[32][33];
    int bx = blockIdx.x, by = blockIdx.y;
    int p0 = bx * 32, c0 = by * 32;
    int t = threadIdx.x, tx = t & 31, ty = t >> 5;
#pragma unroll
    for (int i = 0; i < 4; ++i) {
        size_t off = (size_t)(c0 + ty + 8 * i) * 1024 + p0 + tx;
        float s = 0.f;
#pragma unroll
        for (int b = 0; b < 16; ++b) s += fs[(size_t)b * 524288 + off];
        s *= (1.f / 16.f);
        fsm32[off] = s;
        bf16 h = (bf16)s;
        fsm16[off] = h;
        tile[ty + 8 * i][tx] = h;
    }
    __syncthreads();
#pragma unroll
    for (int i = 0; i < 4; ++i)
        fsmT[(size_t)(p0 + ty + 8 * i) * 512 + c0 + tx] = tile[tx][ty + 8 * i];
    // f_q fp32 -> bf16, 16384 floats per block
    int blk = by * 32 + bx;
    const float4* f4 = (const float4*)fq;
#pragma unroll
    for (int i = 0; i < 16; ++i) {
        int idx = blk * 4096 + i * 256 + t;  // float4 index
        float4 v = f4[idx];
        bf16x4 h4 = {(bf16)v.x, (bf16)v.y, (bf16)v.z, (bf16)v.w};
        *(bf16x4*)(fq16 + (size_t)idx * 4) = h4;
    }
}

// K1: rm[c] = rowmean(fs_mean[c,:]); u[c] = wsq[c]*wsk[c]*rm[c]/256
__global__ void k_u(const float* __restrict__ fsm32, const float* __restrict__ wsq,
                    const float* __restrict__ wsk, float* __restrict__ u,
                    float* __restrict__ rm) {
    int c = blockIdx.x;
    int t = threadIdx.x;
    float s = 0.f;
#pragma unroll
    for (int j = 0; j < 4; ++j) s += fsm32[(size_t)c * 1024 + t + 256 * j];
    s = wave_reduce_sum(s);
    __shared__ float red[4];
    int w = t >> 6, lane = t & 63;
    if (lane == 0) red[w] = s;
    __syncthreads();
    if (t == 0) {
        float rmv = (red[0] + red[1] + red[2] + red[3]) * (1.f / 1024.f);
        rm[c] = rmv;
        u[c] = wsq[c] * wsk[c] * rmv * (1.f / 256.f);
    }
}

// K2: G[b,c,d] = sum_p fq16[b,c,p]*fsm16[d,p] — 64(c)x128(d) LDS tile, K=1024
// grid (4 dt, 8 ct, 16 b), 2 blocks/CU.
__global__ void k_gemm1(const bf16* __restrict__ A, const bf16* __restrict__ B,
                        float* __restrict__ G) {
    __shared__ alignas(16) bf16 As[64 * 32];
    __shared__ alignas(16) bf16 Bs[128 * 32];
    const int dt = blockIdx.x, ct = blockIdx.y, b = blockIdx.z;
    const int t = threadIdx.x, w = t >> 6, lane = t & 63;
    const int quad = lane >> 4, r15 = lane & 15;
    const bf16* Abase = A + ((size_t)(b * 512 + ct * 64)) * 1024;
    const bf16* Bbase = B + ((size_t)(dt * 128)) * 1024;
    const int sr = t >> 2, sc = (t & 3) * 8;
    f32x4 acc[8] = {};
    for (int k0 = 0; k0 < 1024; k0 += 32) {
        GLL16(Abase + (size_t)sr * 1024 + k0 + sc, As + t * 8);
        GLL16(Bbase + (size_t)sr * 1024 + k0 + sc, Bs + t * 8);
        GLL16(Bbase + (size_t)(sr + 64) * 1024 + k0 + sc, Bs + (t + 256) * 8);
        __syncthreads();
        bf16x8 af = *(const bf16x8*)(As + (w * 16 + r15) * 32 + quad * 8);
#pragma unroll
        for (int j = 0; j < 8; ++j) {
            bf16x8 bfr = *(const bf16x8*)(Bs + (j * 16 + r15) * 32 + quad * 8);
            acc[j] = __builtin_amdgcn_mfma_f32_16x16x32_bf16(af, bfr, acc[j], 0, 0, 0);
        }
        __syncthreads();
    }
    float* g = G + ((size_t)(b * 512 + ct * 64 + w * 16 + quad * 4)) * 512 + dt * 128 + r15;
#pragma unroll
    for (int j = 0; j < 8; ++j)
#pragma unroll
        for (int ii = 0; ii < 4; ++ii)
            g[(size_t)ii * 512 + j * 16] = acc[j][ii];
}

// K3: row softmax of G*wq[c]*wk[d]/P -> Acw (folds wv); r[b,c] = sum_d Acw*rm[d]
__global__ void k_softmax_ac(const float* __restrict__ G, const float* __restrict__ wq,
                             const float* __restrict__ wk, const float* __restrict__ wv,
                             const float* __restrict__ rm, bf16* __restrict__ Acw,
                             float* __restrict__ r) {
    int row = blockIdx.x * 4 + (threadIdx.x >> 6);  // b*512 + c
    int lane = threadIdx.x & 63;
    int c = row & 511;
    const float* g = G + (size_t)row * 512;
    float sc = wq[c] * (1.f / 1024.f);
    float v[8];
    float mx = -3.4e38f;
#pragma unroll
    for (int j = 0; j < 8; ++j) {
        int d = lane + 64 * j;
        v[j] = g[d] * sc * wk[d];
        mx = fmaxf(mx, v[j]);
    }
    mx = wave_reduce_max(mx);
    float sum = 0.f;
#pragma unroll
    for (int j = 0; j < 8; ++j) {
        v[j] = __expf(v[j] - mx);
        sum += v[j];
    }
    sum = wave_reduce_sum(sum);
    float inv = 1.f / sum;
    bf16* o = Acw + (size_t)row * 512;
    float rsum = 0.f;
#pragma unroll
    for (int j = 0; j < 8; ++j) {
        int d = lane + 64 * j;
        float aw = v[j] * inv * wv[d];
        o[d] = (bf16)aw;
        rsum += aw * rm[d];
    }
    rsum = wave_reduce_sum(rsum);
    if (lane == 0) r[row] = rsum;
}

// K4: tbp[half,b,d] = sum_{c in half} u[c]*Acw[b,c,d]   (grid (2,16,2))
__global__ void k_t(const bf16* __restrict__ Acw, const float* __restrict__ u,
                    float* __restrict__ tbp) {
    int half = blockIdx.z, b = blockIdx.y;
    int d = blockIdx.x * 256 + threadIdx.x;
    const bf16* base = Acw + (size_t)b * 262144 + (size_t)half * 256 * 512 + d;
    const float* uu = u + half * 256;
    float s = 0.f;
#pragma unroll 16
    for (int c = 0; c < 256; ++c) s += uu[c] * (float)base[(size_t)c * 512];
    tbp[(half * 16 + b) * 512 + d] = s;
}

// K5: out[b,c,p] = fq + lam*sum_d Acw[b,c,d]*fsmT[p,d] — 64(c)x128(p) tile, K=512
// grid (8 pt, 8 ct, 16 b), 4 blocks/CU.
__global__ void k_gemm2(const bf16* __restrict__ A, const bf16* __restrict__ B,
                        const float* __restrict__ fq, const float* __restrict__ lamp,
                        float* __restrict__ out) {
    __shared__ alignas(16) bf16 As[64 * 32];
    __shared__ alignas(16) bf16 Bs[128 * 32];
    const int pt = blockIdx.x, ct = blockIdx.y, b = blockIdx.z;
    const int t = threadIdx.x, w = t >> 6, lane = t & 63;
    const int quad = lane >> 4, r15 = lane & 15;
    const bf16* Abase = A + ((size_t)(b * 512 + ct * 64)) * 512;
    const bf16* Bbase = B + ((size_t)(pt * 128)) * 512;
    const int sr = t >> 2, sc = (t & 3) * 8;
    f32x4 acc[8] = {};
    for (int k0 = 0; k0 < 512; k0 += 32) {
        GLL16(Abase + (size_t)sr * 512 + k0 + sc, As + t * 8);
        GLL16(Bbase + (size_t)sr * 512 + k0 + sc, Bs + t * 8);
        GLL16(Bbase + (size_t)(sr + 64) * 512 + k0 + sc, Bs + (t + 256) * 8);
        __syncthreads();
        bf16x8 af = *(const bf16x8*)(As + (w * 16 + r15) * 32 + quad * 8);
#pragma unroll
        for (int j = 0; j < 8; ++j) {
            bf16x8 bfr = *(const bf16x8*)(Bs + (j * 16 + r15) * 32 + quad * 8);
            acc[j] = __builtin_amdgcn_mfma_f32_16x16x32_bf16(af, bfr, acc[j], 0, 0, 0);
        }
        __syncthreads();
    }
    float lam = lamp[0];
    size_t rowbase = (size_t)(b * 512 + ct * 64 + w * 16 + quad * 4);
#pragma unroll
    for (int j = 0; j < 8; ++j)
#pragma unroll
        for (int ii = 0; ii < 4; ++ii) {
            size_t idx = (rowbase + ii) * 1024 + pt * 128 + j * 16 + r15;
            out[idx] = fq[idx] + lam * acc[j][ii];
        }
}

// K6: z<16: alog[b,p] = sum_d (tbp0+tbp1)[b,d]*fsm[d,p]; z>=16: blog via r
__global__ void k_logits(const float* __restrict__ tbp, const float* __restrict__ r,
                         const float* __restrict__ wsq, const float* __restrict__ wsk,
                         const float* __restrict__ fsm32, float* __restrict__ alog,
                         float* __restrict__ blog) {
    int z = blockIdx.y, pq = blockIdx.x * 256 + threadIdx.x;
    if (z < 16) {
        const float* t0 = tbp + z * 512;
        const float* t1 = tbp + (16 + z) * 512;
        float s = 0.f;
#pragma unroll 8
        for (int d = 0; d < 512; ++d) s += (t0[d] + t1[d]) * fsm32[(size_t)d * 1024 + pq];
        alog[z * 1024 + pq] = s;
    } else {
        int b = z - 16;
        float s = 0.f;
#pragma unroll 8
        for (int c = 0; c < 512; ++c) {
            float coef = r[b * 512 + c] * wsq[c] * wsk[c] * (1.f / 256.f);
            s += coef * fsm32[(size_t)c * 1024 + pq];
        }
        blog[b * 1024 + pq] = s;
    }
}

// K7: z<16: alpha softmax -> out; z>=16: beta softmax -> ws
__global__ void k_softmax_rows(const float* __restrict__ alog, const float* __restrict__ blog,
                               float* __restrict__ alpha_out, float* __restrict__ beta) {
    int z = blockIdx.x;
    int t = threadIdx.x;
    int w = t >> 6, lane = t & 63;
    const float* src = (z < 16) ? (alog + (size_t)z * 1024) : (blog + (size_t)(z - 16) * 1024);
    float v[4];
    float mx = -3.4e38f;
#pragma unroll
    for (int j = 0; j < 4; ++j) {
        v[j] = src[t + 256 * j];
        mx = fmaxf(mx, v[j]);
    }
    __shared__ float red[4];
    float wm = wave_reduce_max(mx);
    if (lane == 0) red[w] = wm;
    __syncthreads();
    mx = fmaxf(fmaxf(red[0], red[1]), fmaxf(red[2], red[3]));
    float s = 0.f;
#pragma unroll
    for (int j = 0; j < 4; ++j) {
        v[j] = __expf(v[j] - mx);
        s += v[j];
    }
    __syncthreads();
    float ws_ = wave_reduce_sum(s);
    if (lane == 0) red[w] = ws_;
    __syncthreads();
    s = red[0] + red[1] + red[2] + red[3];
    float inv = 1.f / s;
    if (z < 16) {
#pragma unroll
        for (int j = 0; j < 4; ++j) alpha_out[(size_t)z * 1024 + t + 256 * j] = v[j] * inv;
    } else {
#pragma unroll
        for (int j = 0; j < 4; ++j) beta[(size_t)(z - 16) * 1024 + t + 256 * j] = v[j] * inv;
    }
}

// K8: beta_mean broadcast
__global__ void k_betamean(const float* __restrict__ beta, float* __restrict__ out) {
    int q = blockIdx.x * 256 + threadIdx.x;
    float s = 0.f;
#pragma unroll
    for (int b = 0; b < 16; ++b) s += beta[b * 1024 + q];
    float val = s * (1.f / 16.f);
#pragma unroll
    for (int si = 0; si < 16; ++si) out[(size_t)si * 1024 + q] = val;
}

extern "C" void kernel_launch(void* const* d_in, const int* in_sizes, int n_in,
                              void* d_out, int out_size, void* d_ws, size_t ws_size,
                              hipStream_t stream) {
    const float* f_q = (const float*)d_in[0];
    const float* f_s = (const float*)d_in[1];
    const float* w_cca_q = (const float*)d_in[2];
    const float* w_cca_k = (const float*)d_in[3];
    const float* w_cca_v = (const float*)d_in[4];
    const float* w_sca_q = (const float*)d_in[5];
    const float* w_sca_k = (const float*)d_in[6];
    const float* lamp = (const float*)d_in[7];

    char* ws = (char*)d_ws;
    float* fsm32 = (float*)(ws + 0);             //  2 MB   [512,1024]
    bf16* fsm16 = (bf16*)(ws + 2097152);         //  1 MB
    bf16* fsmT = (bf16*)(ws + 3145728);          //  1 MB   [1024,512]
    float* G = (float*)(ws + 4194304);           // 16 MB   [16,512,512]
    bf16* Acw = (bf16*)(ws + 20971520);          //  8 MB   [16,512,512]
    bf16* fq16 = (bf16*)(ws + 29360128);         // 16.8 MB [16,512,1024]
    float* rm = (float*)(ws + 46137344);         //  2 KB
    float* u = (float*)(ws + 46139392);          //  2 KB
    float* r = (float*)(ws + 46141440);          // 32 KB   [16,512]
    float* tbp = (float*)(ws + 46174208);        // 64 KB   [32,512]
    float* alog = (float*)(ws + 46239744);       // 64 KB
    float* blog = (float*)(ws + 46305280);       // 64 KB
    float* beta = (float*)(ws + 46370816);       // 64 KB

    float* out_fq = (float*)d_out;
    float* out_alpha = out_fq + 8388608;
    float* out_bmean = out_fq + 8404992;

    k_prep<<<dim3(32, 16), 256, 0, stream>>>(f_s, f_q, fsm32, fsm16, fsmT, fq16);
    k_u<<<512, 256, 0, stream>>>(fsm32, w_sca_q, w_sca_k, u, rm);
    k_gemm1<<<dim3(4, 8, 16), 256, 0, stream>>>(fq16, fsm16, G);
    k_softmax_ac<<<2048, 256, 0, stream>>>(G, w_cca_q, w_cca_k, w_cca_v, rm, Acw, r);
    k_t<<<dim3(2, 16, 2), 256, 0, stream>>>(Acw, u, tbp);
    k_gemm2<<<dim3(8, 8, 16), 256, 0, stream>>>(Acw, fsmT, f_q, lamp, out_fq);
    k_logits<<<dim3(4, 32), 256, 0, stream>>>(tbp, r, w_sca_q, w_sca_k, fsm32, alog, blog);
    k_softmax_rows<<<32, 256, 0, stream>>>(alog, blog, out_alpha, beta);
    k_betamean<<<4, 256, 0, stream>>>(beta, out_bmean);
}